// Round 4
// baseline (109.614 us; speedup 1.0000x reference)
//
#include <hip/hip_runtime.h>
#include <hip/hip_bf16.h>
#include <math.h>

// Problem constants: R,C,D,ORDER = 2048,2048,64,3; O=4
#define R_DIM 2048
#define C_DIM 2048
#define D_DIM 64
// Factorization: dist^2[r,c] = sum_k A[r,k]*B[c,k] + ||zc||^2 with
//   k in [0,256): A = z_rows[o][r][d], B = -2*coef_o(t_c)*z_cols[c][d]
//   k in [256,272): A = Gram[r] (4x4), B = coef_o*coef_o' products
//   k in [272,288): zero pad
// Split-K phases (LDS <= 64KB static limit):
//   phase A: global k [0,128)   (orders 0,1)        klocal [0,128)
//   phase B: global k [128,288) (orders 2,3 + Gram) klocal [0,160)
#define KSTRIDE 168  // LDS row stride in bf16 elems (160 + 8 pad -> 2-way banks, free)

typedef __attribute__((ext_vector_type(8))) short short8;   // bf16x8 MFMA frag
typedef __attribute__((ext_vector_type(4))) float floatx4;  // fp32x4 acc

__device__ __forceinline__ ushort f2bf(float f) {  // RNE float->bf16
  unsigned u = __float_as_uint(f);
  return (ushort)((u + 0x7FFFu + ((u >> 16) & 1u)) >> 16);
}
__device__ __forceinline__ ushort4 pack4(float4 v) {
  ushort4 r;
  r.x = f2bf(v.x); r.y = f2bf(v.y); r.z = f2bf(v.z); r.w = f2bf(v.w);
  return r;
}
__device__ __forceinline__ float4 scale4(float s, float4 v) {
  float4 r;
  r.x = s * v.x; r.y = s * v.y; r.z = s * v.z; r.w = s * v.w;
  return r;
}
__device__ __forceinline__ float dot4(float4 a, float4 b) {
  return fmaf(a.x, b.x, fmaf(a.y, b.y, fmaf(a.z, b.z, a.w * b.w)));
}

// One fused kernel: per-block bf16 tile build + barrier-free MFMA runs +
// softplus epilogue + last-block final reduction (no separate prep dispatch).
// 64x64 tile, 256 thr = 4 waves (2x2 of 32x32), grid 32x32 = 1024 blocks.
// LDS 43.3KB -> 3 blocks/CU.
__launch_bounds__(256, 3)
__global__ void fused_kernel(const int* __restrict__ events,
                             const float* __restrict__ col_times,
                             const float* __restrict__ z_rows,
                             const float* __restrict__ z_cols,
                             const float* __restrict__ gamma_rows,
                             const float* __restrict__ gamma_cols,
                             unsigned* __restrict__ cnt,
                             float* __restrict__ parts,
                             float* __restrict__ out) {
  __shared__ __align__(16) ushort As[64 * KSTRIDE];  // [row][klocal]
  __shared__ __align__(16) ushort Bs[64 * KSTRIDE];  // [col][klocal]
  __shared__ float nzc_s[64];
  __shared__ float red[4];
  __shared__ float flag;

  const int t = threadIdx.x;
  const int widx = t >> 6, lane = t & 63;
  const int m0 = blockIdx.y * 64, c0 = blockIdx.x * 64;
  const int wm = widx & 1, wn = widx >> 1;  // wave pos in 2x2
  const int lm = lane & 15, kg = lane >> 4;

  // staging assignment: thread -> (tile row/col rr, 16-wide d-chunk ch)
  const int rr = t >> 2;
  const int ch = t & 3;
  const int d0 = ch * 16;

  // ---- fp32 global loads (all upfront; z data is L2-resident) ----
  float4 av[4][4];  // av[o][i]: z_rows[o][m0+rr][d0+4i..+4]
#pragma unroll
  for (int o = 0; o < 4; ++o)
#pragma unroll
    for (int i = 0; i < 4; ++i)
      av[o][i] = *(const float4*)&z_rows[(size_t)(o * R_DIM + m0 + rr) * D_DIM + d0 + i * 4];
  float4 bv[4];  // z_cols[c0+rr][d0+4i..]
#pragma unroll
  for (int i = 0; i < 4; ++i)
    bv[i] = *(const float4*)&z_cols[(size_t)(c0 + rr) * D_DIM + d0 + i * 4];
  const float tt = col_times[c0 + rr];
  float cf[4];
  cf[0] = 1.0f; cf[1] = tt; cf[2] = tt * tt * 0.5f; cf[3] = cf[2] * tt * (1.0f / 3.0f);

  // ---- phase A staging: orders 0,1 -> klocal [0,128) ----
#pragma unroll
  for (int o = 0; o < 2; ++o) {
    const float s = -2.0f * cf[o];
#pragma unroll
    for (int i = 0; i < 4; ++i) {
      *(ushort4*)&As[rr * KSTRIDE + o * 64 + d0 + i * 4] = pack4(av[o][i]);
      *(ushort4*)&Bs[rr * KSTRIDE + o * 64 + d0 + i * 4] = pack4(scale4(s, bv[i]));
    }
  }
  // nzc: ||z_col||^2 (fp32, 4-thread reduce)
  float q = dot4(bv[0], bv[0]) + dot4(bv[1], bv[1]) + dot4(bv[2], bv[2]) + dot4(bv[3], bv[3]);
  q += __shfl_xor(q, 1); q += __shfl_xor(q, 2);
  if (ch == 0) nzc_s[rr] = q;

  __syncthreads();

  floatx4 acc[2][2];
#pragma unroll
  for (int i = 0; i < 2; ++i)
#pragma unroll
    for (int j = 0; j < 2; ++j) acc[i][j] = (floatx4){0.f, 0.f, 0.f, 0.f};

  // phase A MFMA: 4 k-tiles, no barriers inside
#pragma unroll
  for (int kt = 0; kt < 128; kt += 32) {
    short8 a[2], b[2];
#pragma unroll
    for (int mt = 0; mt < 2; ++mt)
      a[mt] = *(const short8*)&As[(wm * 32 + mt * 16 + lm) * KSTRIDE + kt + kg * 8];
#pragma unroll
    for (int nt = 0; nt < 2; ++nt)
      b[nt] = *(const short8*)&Bs[(wn * 32 + nt * 16 + lm) * KSTRIDE + kt + kg * 8];
#pragma unroll
    for (int mt = 0; mt < 2; ++mt)
#pragma unroll
      for (int nt = 0; nt < 2; ++nt)
        acc[mt][nt] = __builtin_amdgcn_mfma_f32_16x16x32_bf16(a[mt], b[nt], acc[mt][nt], 0, 0, 0);
  }

  __syncthreads();  // all reads done before phase-B overwrite

  // ---- phase B staging: orders 2,3 -> klocal [0,128); Gram/coef -> [128,144);
  //      zeros [144,160) ----
#pragma unroll
  for (int o = 2; o < 4; ++o) {
    const float s = -2.0f * cf[o];
#pragma unroll
    for (int i = 0; i < 4; ++i) {
      *(ushort4*)&As[rr * KSTRIDE + (o - 2) * 64 + d0 + i * 4] = pack4(av[o][i]);
      *(ushort4*)&Bs[rr * KSTRIDE + (o - 2) * 64 + d0 + i * 4] = pack4(scale4(s, bv[i]));
    }
  }
  // Gram: 10 unique dots over D=64 in fp32 (4-thread reduce)
  float g[10];
#pragma unroll
  for (int p = 0; p < 10; ++p) g[p] = 0.0f;
#pragma unroll
  for (int i = 0; i < 4; ++i) {
    const float4 a0 = av[0][i], a1 = av[1][i], a2 = av[2][i], a3 = av[3][i];
    g[0] += dot4(a0, a0); g[1] += dot4(a0, a1); g[2] += dot4(a0, a2);
    g[3] += dot4(a0, a3); g[4] += dot4(a1, a1); g[5] += dot4(a1, a2);
    g[6] += dot4(a1, a3); g[7] += dot4(a2, a2); g[8] += dot4(a2, a3);
    g[9] += dot4(a3, a3);
  }
#pragma unroll
  for (int p = 0; p < 10; ++p) {
    g[p] += __shfl_xor(g[p], 1);
    g[p] += __shfl_xor(g[p], 2);
  }
  if (ch == 0) {
    ushort* ea = &As[rr * KSTRIDE + 128];  // full symmetric 4x4 Gram, then pad
    ea[0] = f2bf(g[0]); ea[1] = f2bf(g[1]); ea[2] = f2bf(g[2]); ea[3] = f2bf(g[3]);
    ea[4] = f2bf(g[1]); ea[5] = f2bf(g[4]); ea[6] = f2bf(g[5]); ea[7] = f2bf(g[6]);
    ea[8] = f2bf(g[2]); ea[9] = f2bf(g[5]); ea[10] = f2bf(g[7]); ea[11] = f2bf(g[8]);
    ea[12] = f2bf(g[3]); ea[13] = f2bf(g[6]); ea[14] = f2bf(g[8]); ea[15] = f2bf(g[9]);
#pragma unroll
    for (int z = 16; z < 32; ++z) ea[z] = 0;
    ushort* eb = &Bs[rr * KSTRIDE + 128];  // coef outer products, then pad
#pragma unroll
    for (int i = 0; i < 16; ++i) eb[i] = f2bf(cf[i >> 2] * cf[i & 3]);
#pragma unroll
    for (int z = 16; z < 32; ++z) eb[z] = 0;
  }
  __syncthreads();

  // phase B MFMA: 5 k-tiles (klocal 0..160), no barriers inside
#pragma unroll
  for (int kt = 0; kt < 160; kt += 32) {
    short8 a[2], b[2];
#pragma unroll
    for (int mt = 0; mt < 2; ++mt)
      a[mt] = *(const short8*)&As[(wm * 32 + mt * 16 + lm) * KSTRIDE + kt + kg * 8];
#pragma unroll
    for (int nt = 0; nt < 2; ++nt)
      b[nt] = *(const short8*)&Bs[(wn * 32 + nt * 16 + lm) * KSTRIDE + kt + kg * 8];
#pragma unroll
    for (int mt = 0; mt < 2; ++mt)
#pragma unroll
      for (int nt = 0; nt < 2; ++nt)
        acc[mt][nt] = __builtin_amdgcn_mfma_f32_16x16x32_bf16(a[mt], b[nt], acc[mt][nt], 0, 0, 0);
  }

  // ---- epilogue: C/D layout (m89): col = lane&15, row = (lane>>4)*4 + reg ----
  float gc[2], nz[2];
  int cidx[2];
#pragma unroll
  for (int nt = 0; nt < 2; ++nt) {
    const int c = c0 + wn * 32 + nt * 16 + lm;
    cidx[nt] = c;
    gc[nt] = gamma_cols[c];
    nz[nt] = nzc_s[c - c0];
  }
  float lsum = 0.0f;
#pragma unroll
  for (int mt = 0; mt < 2; ++mt) {
    const int rbase = m0 + wm * 32 + mt * 16 + kg * 4;
#pragma unroll
    for (int j = 0; j < 4; ++j) {
      const int r = rbase + j;
      const float gr = gamma_rows[r];
#pragma unroll
      for (int nt = 0; nt < 2; ++nt) {
        const int ev = events[(size_t)r * C_DIM + cidx[nt]];  // read exactly once globally
        const float d2 = acc[mt][nt][j] + nz[nt];
        const float dist = sqrtf(fmaxf(d2, 0.0f));
        const float logit = gr + gc[nt] - dist;
        const float x = ev ? -logit : logit;  // softplus(-sign*logit)
        lsum += fmaxf(x, 0.0f) + __logf(1.0f + __expf(-fabsf(x)));
      }
    }
  }
#pragma unroll
  for (int off = 32; off > 0; off >>= 1) lsum += __shfl_down(lsum, off);
  if (lane == 0) red[widx] = lsum;
  __syncthreads();

  // ---- block partial -> ws; last block reduces all partials -> out ----
  const int bid = blockIdx.y * gridDim.x + blockIdx.x;
  if (t == 0) {
    const float bs = red[0] + red[1] + red[2] + red[3];
    atomicExch(&parts[bid], bs);    // device-scope write of partial
    __threadfence();                 // order partial before arrival tick
    const unsigned old = atomicAdd(cnt, 1u);
    flag = (old == 1023u) ? 1.0f : 0.0f;
  }
  __syncthreads();
  if (flag != 0.0f) {
    __threadfence();
    float s = 0.0f;
    for (int i = t; i < 1024; i += 256) s += atomicAdd(&parts[i], 0.0f);  // atomic read
#pragma unroll
    for (int off = 32; off > 0; off >>= 1) s += __shfl_down(s, off);
    if (lane == 0) red[widx] = s;
    __syncthreads();
    if (t == 0) out[0] = red[0] + red[1] + red[2] + red[3];
  }
}

extern "C" void kernel_launch(void* const* d_in, const int* in_sizes, int n_in,
                              void* d_out, int out_size, void* d_ws, size_t ws_size,
                              hipStream_t stream) {
  const int* events = (const int*)d_in[0];
  const float* col_times = (const float*)d_in[1];
  const float* z_rows = (const float*)d_in[2];
  const float* z_cols = (const float*)d_in[3];
  const float* gamma_rows = (const float*)d_in[4];
  const float* gamma_cols = (const float*)d_in[5];

  unsigned* cnt = (unsigned*)d_ws;           // arrival counter (needs 0 init)
  float* parts = (float*)d_ws + 16;          // 1024 block partials (no init needed)
  hipMemsetAsync(d_ws, 0, 4, stream);        // capture-legal memset node

  dim3 grid(C_DIM / 64, R_DIM / 64);
  fused_kernel<<<grid, 256, 0, stream>>>(events, col_times, z_rows, z_cols,
                                         gamma_rows, gamma_cols, cnt, parts,
                                         (float*)d_out);
}

// Round 5
// 106.995 us; speedup vs baseline: 1.0245x; 1.0245x over previous
//
#include <hip/hip_runtime.h>
#include <hip/hip_bf16.h>
#include <math.h>

// Problem constants: R,C,D,ORDER = 2048,2048,64,3; O=4
#define R_DIM 2048
#define C_DIM 2048
#define D_DIM 64
// Factorization: dist^2[r,c] = sum_k A[r,k]*B[c,k] + ||zc||^2 with
//   k in [0,256): A = z_rows[o][r][d], B = -2*coef_o(t_c)*z_cols[c][d]
//   k in [256,272): A = Gram[r] (4x4), B = coef_o*coef_o' products
// Split-K phases: A: orders 0,1 (k 0..128); B: orders 2,3 + Gram (k 0..160)
#define KSTRIDE 168  // LDS row stride in bf16 elems (160 + 8 pad)

typedef __attribute__((ext_vector_type(8))) short short8;   // bf16x8 MFMA frag
typedef __attribute__((ext_vector_type(4))) float floatx4;  // fp32x4 acc

__device__ __forceinline__ ushort f2bf(float f) {  // RNE float->bf16
  unsigned u = __float_as_uint(f);
  return (ushort)((u + 0x7FFFu + ((u >> 16) & 1u)) >> 16);
}
__device__ __forceinline__ ushort4 pack4(float4 v) {
  ushort4 r;
  r.x = f2bf(v.x); r.y = f2bf(v.y); r.z = f2bf(v.z); r.w = f2bf(v.w);
  return r;
}
__device__ __forceinline__ float4 scale4(float s, float4 v) {
  float4 r;
  r.x = s * v.x; r.y = s * v.y; r.z = s * v.z; r.w = s * v.w;
  return r;
}
__device__ __forceinline__ float dot4(float4 a, float4 b) {
  return fmaf(a.x, b.x, fmaf(a.y, b.y, fmaf(a.z, b.z, a.w * b.w)));
}

// One fused kernel. 64x64 tile, 256 thr = 4 waves (2x2 of 32x32 wave tiles),
// grid 32x32 = 1024 blocks. LDS ~47.4KB -> 3 blocks/CU.
// Events: coalesced int4 loads issued at kernel START (4 x 16B/thread),
// parked in VGPRs across the GEMM, packed to a dedicated LDS byte tile after
// the last MFMA, consumed by the epilogue -> HBM latency fully overlapped.
__launch_bounds__(256, 3)
__global__ void fused_kernel(const int* __restrict__ events,
                             const float* __restrict__ col_times,
                             const float* __restrict__ z_rows,
                             const float* __restrict__ z_cols,
                             const float* __restrict__ gamma_rows,
                             const float* __restrict__ gamma_cols,
                             unsigned* __restrict__ cnt,
                             float* __restrict__ parts,
                             float* __restrict__ out) {
  __shared__ __align__(16) ushort As[64 * KSTRIDE];  // [row][klocal]
  __shared__ __align__(16) ushort Bs[64 * KSTRIDE];  // [col][klocal]
  __shared__ __align__(16) unsigned char Evb[64 * 64];  // event tile bytes
  __shared__ float nzc_s[64];
  __shared__ float red[4];
  __shared__ float flag;

  const int t = threadIdx.x;
  const int widx = t >> 6, lane = t & 63;
  const int m0 = blockIdx.y * 64, c0 = blockIdx.x * 64;
  const int wm = widx & 1, wn = widx >> 1;  // wave pos in 2x2
  const int lm = lane & 15, kg = lane >> 4;

  // staging assignment: thread -> (tile row/col rr, 16-wide d-chunk ch)
  const int rr = t >> 2;
  const int ch = t & 3;
  const int d0 = ch * 16;

  // ---- fp32 z loads (needed first) ----
  float4 av[4][4];  // av[o][i]: z_rows[o][m0+rr][d0+4i..+4]
#pragma unroll
  for (int o = 0; o < 4; ++o)
#pragma unroll
    for (int i = 0; i < 4; ++i)
      av[o][i] = *(const float4*)&z_rows[(size_t)(o * R_DIM + m0 + rr) * D_DIM + d0 + i * 4];
  float4 bv[4];  // z_cols[c0+rr][d0+4i..]
#pragma unroll
  for (int i = 0; i < 4; ++i)
    bv[i] = *(const float4*)&z_cols[(size_t)(c0 + rr) * D_DIM + d0 + i * 4];
  const float tt = col_times[c0 + rr];

  // ---- events tile: coalesced int4 loads, issued NOW, consumed at the end.
  // load i covers row (i*16 + t/16), cols (t%16)*4 .. +4  (16B granules)
  const int erow = t >> 4;        // 0..15
  const int ecol = (t & 15) * 4;  // 0..60
  int4 evr[4];
#pragma unroll
  for (int i = 0; i < 4; ++i)
    evr[i] = *(const int4*)&events[(size_t)(m0 + i * 16 + erow) * C_DIM + c0 + ecol];

  float cf[4];
  cf[0] = 1.0f; cf[1] = tt; cf[2] = tt * tt * 0.5f; cf[3] = cf[2] * tt * (1.0f / 3.0f);

  // ---- phase A staging: orders 0,1 -> klocal [0,128) ----
#pragma unroll
  for (int o = 0; o < 2; ++o) {
    const float s = -2.0f * cf[o];
#pragma unroll
    for (int i = 0; i < 4; ++i) {
      *(ushort4*)&As[rr * KSTRIDE + o * 64 + d0 + i * 4] = pack4(av[o][i]);
      *(ushort4*)&Bs[rr * KSTRIDE + o * 64 + d0 + i * 4] = pack4(scale4(s, bv[i]));
    }
  }
  // nzc: ||z_col||^2 (fp32, 4-thread reduce)
  float q = dot4(bv[0], bv[0]) + dot4(bv[1], bv[1]) + dot4(bv[2], bv[2]) + dot4(bv[3], bv[3]);
  q += __shfl_xor(q, 1); q += __shfl_xor(q, 2);
  if (ch == 0) nzc_s[rr] = q;

  __syncthreads();

  floatx4 acc[2][2];
#pragma unroll
  for (int i = 0; i < 2; ++i)
#pragma unroll
    for (int j = 0; j < 2; ++j) acc[i][j] = (floatx4){0.f, 0.f, 0.f, 0.f};

  // phase A MFMA: 4 k-tiles, no barriers inside
#pragma unroll
  for (int kt = 0; kt < 128; kt += 32) {
    short8 a[2], b[2];
#pragma unroll
    for (int mt = 0; mt < 2; ++mt)
      a[mt] = *(const short8*)&As[(wm * 32 + mt * 16 + lm) * KSTRIDE + kt + kg * 8];
#pragma unroll
    for (int nt = 0; nt < 2; ++nt)
      b[nt] = *(const short8*)&Bs[(wn * 32 + nt * 16 + lm) * KSTRIDE + kt + kg * 8];
#pragma unroll
    for (int mt = 0; mt < 2; ++mt)
#pragma unroll
      for (int nt = 0; nt < 2; ++nt)
        acc[mt][nt] = __builtin_amdgcn_mfma_f32_16x16x32_bf16(a[mt], b[nt], acc[mt][nt], 0, 0, 0);
  }

  __syncthreads();  // all phase-A reads done before overwrite

  // ---- phase B staging: orders 2,3 -> [0,128); Gram/coef -> [128,144); pad ----
#pragma unroll
  for (int o = 2; o < 4; ++o) {
    const float s = -2.0f * cf[o];
#pragma unroll
    for (int i = 0; i < 4; ++i) {
      *(ushort4*)&As[rr * KSTRIDE + (o - 2) * 64 + d0 + i * 4] = pack4(av[o][i]);
      *(ushort4*)&Bs[rr * KSTRIDE + (o - 2) * 64 + d0 + i * 4] = pack4(scale4(s, bv[i]));
    }
  }
  // Gram: 10 unique dots over D=64 in fp32 (4-thread reduce)
  float g[10];
#pragma unroll
  for (int p = 0; p < 10; ++p) g[p] = 0.0f;
#pragma unroll
  for (int i = 0; i < 4; ++i) {
    const float4 a0 = av[0][i], a1 = av[1][i], a2 = av[2][i], a3 = av[3][i];
    g[0] += dot4(a0, a0); g[1] += dot4(a0, a1); g[2] += dot4(a0, a2);
    g[3] += dot4(a0, a3); g[4] += dot4(a1, a1); g[5] += dot4(a1, a2);
    g[6] += dot4(a1, a3); g[7] += dot4(a2, a2); g[8] += dot4(a2, a3);
    g[9] += dot4(a3, a3);
  }
#pragma unroll
  for (int p = 0; p < 10; ++p) {
    g[p] += __shfl_xor(g[p], 1);
    g[p] += __shfl_xor(g[p], 2);
  }
  if (ch == 0) {
    ushort* ea = &As[rr * KSTRIDE + 128];  // full symmetric 4x4 Gram, then pad
    ea[0] = f2bf(g[0]); ea[1] = f2bf(g[1]); ea[2] = f2bf(g[2]); ea[3] = f2bf(g[3]);
    ea[4] = f2bf(g[1]); ea[5] = f2bf(g[4]); ea[6] = f2bf(g[5]); ea[7] = f2bf(g[6]);
    ea[8] = f2bf(g[2]); ea[9] = f2bf(g[5]); ea[10] = f2bf(g[7]); ea[11] = f2bf(g[8]);
    ea[12] = f2bf(g[3]); ea[13] = f2bf(g[6]); ea[14] = f2bf(g[8]); ea[15] = f2bf(g[9]);
#pragma unroll
    for (int z = 16; z < 32; ++z) ea[z] = 0;
    ushort* eb = &Bs[rr * KSTRIDE + 128];  // coef outer products, then pad
#pragma unroll
    for (int i = 0; i < 16; ++i) eb[i] = f2bf(cf[i >> 2] * cf[i & 3]);
#pragma unroll
    for (int z = 16; z < 32; ++z) eb[z] = 0;
  }
  __syncthreads();

  // phase B MFMA: 5 k-tiles, no barriers inside
#pragma unroll
  for (int kt = 0; kt < 160; kt += 32) {
    short8 a[2], b[2];
#pragma unroll
    for (int mt = 0; mt < 2; ++mt)
      a[mt] = *(const short8*)&As[(wm * 32 + mt * 16 + lm) * KSTRIDE + kt + kg * 8];
#pragma unroll
    for (int nt = 0; nt < 2; ++nt)
      b[nt] = *(const short8*)&Bs[(wn * 32 + nt * 16 + lm) * KSTRIDE + kt + kg * 8];
#pragma unroll
    for (int mt = 0; mt < 2; ++mt)
#pragma unroll
      for (int nt = 0; nt < 2; ++nt)
        acc[mt][nt] = __builtin_amdgcn_mfma_f32_16x16x32_bf16(a[mt], b[nt], acc[mt][nt], 0, 0, 0);
  }

  // ---- park prefetched events into LDS byte tile (dedicated buffer) ----
#pragma unroll
  for (int i = 0; i < 4; ++i) {
    uchar4 pk;
    pk.x = (unsigned char)evr[i].x; pk.y = (unsigned char)evr[i].y;
    pk.z = (unsigned char)evr[i].z; pk.w = (unsigned char)evr[i].w;
    *(uchar4*)&Evb[(i * 16 + erow) * 64 + ecol] = pk;
  }
  __syncthreads();

  // ---- epilogue: C/D layout (m89): col = lane&15, row = (lane>>4)*4 + reg.
  // softplus(-s*logit) = softplus(logit) - ev*logit  (branchless)
  float gc[2], nz[2];
  int cl[2];
#pragma unroll
  for (int nt = 0; nt < 2; ++nt) {
    const int c = c0 + wn * 32 + nt * 16 + lm;
    cl[nt] = wn * 32 + nt * 16 + lm;
    gc[nt] = gamma_cols[c];
    nz[nt] = nzc_s[cl[nt]];
  }
  float lsum = 0.0f;
#pragma unroll
  for (int mt = 0; mt < 2; ++mt) {
    const int rl = wm * 32 + mt * 16 + kg * 4;
#pragma unroll
    for (int j = 0; j < 4; ++j) {
      const float gr = gamma_rows[m0 + rl + j];
#pragma unroll
      for (int nt = 0; nt < 2; ++nt) {
        const float evf = (float)Evb[(rl + j) * 64 + cl[nt]];
        const float d2 = acc[mt][nt][j] + nz[nt];
        const float dist = sqrtf(fmaxf(d2, 0.0f));
        const float logit = gr + gc[nt] - dist;
        lsum += fmaxf(logit, 0.0f) + __logf(1.0f + __expf(-fabsf(logit))) - evf * logit;
      }
    }
  }
#pragma unroll
  for (int off = 32; off > 0; off >>= 1) lsum += __shfl_down(lsum, off);
  if (lane == 0) red[widx] = lsum;
  __syncthreads();

  // ---- block partial -> ws; last block reduces all partials -> out ----
  const int bid = blockIdx.y * gridDim.x + blockIdx.x;
  if (t == 0) {
    const float bs = red[0] + red[1] + red[2] + red[3];
    atomicExch(&parts[bid], bs);  // device-scope write of partial
    __threadfence();
    const unsigned old = atomicAdd(cnt, 1u);
    flag = (old == 1023u) ? 1.0f : 0.0f;
  }
  __syncthreads();
  if (flag != 0.0f) {
    __threadfence();
    float s = 0.0f;
    for (int i = t; i < 1024; i += 256) s += atomicAdd(&parts[i], 0.0f);  // atomic read
#pragma unroll
    for (int off = 32; off > 0; off >>= 1) s += __shfl_down(s, off);
    if (lane == 0) red[widx] = s;
    __syncthreads();
    if (t == 0) out[0] = red[0] + red[1] + red[2] + red[3];
  }
}

extern "C" void kernel_launch(void* const* d_in, const int* in_sizes, int n_in,
                              void* d_out, int out_size, void* d_ws, size_t ws_size,
                              hipStream_t stream) {
  const int* events = (const int*)d_in[0];
  const float* col_times = (const float*)d_in[1];
  const float* z_rows = (const float*)d_in[2];
  const float* z_cols = (const float*)d_in[3];
  const float* gamma_rows = (const float*)d_in[4];
  const float* gamma_cols = (const float*)d_in[5];

  unsigned* cnt = (unsigned*)d_ws;     // arrival counter (needs 0 init)
  float* parts = (float*)d_ws + 16;    // 1024 block partials
  hipMemsetAsync(d_ws, 0, 4, stream);  // capture-legal memset node

  dim3 grid(C_DIM / 64, R_DIM / 64);
  fused_kernel<<<grid, 256, 0, stream>>>(events, col_times, z_rows, z_cols,
                                         gamma_rows, gamma_cols, cnt, parts,
                                         (float*)d_out);
}

// Round 6
// 96.719 us; speedup vs baseline: 1.1333x; 1.1062x over previous
//
#include <hip/hip_runtime.h>
#include <hip/hip_bf16.h>
#include <math.h>

// Problem constants: R,C,D,ORDER = 2048,2048,64,3; O=4
#define R_DIM 2048
#define C_DIM 2048
#define D_DIM 64
// Factorization: dist^2[r,c] = sum_k A[r,k]*B[c,k] + ||zc||^2 with
//   k in [0,256): A = z_rows[o][r][d], B = -2*coef_o(t_c)*z_cols[c][d]
//   k in [256,272): A = Gram[r] (4x4 row-major), B = coef_o*coef_o' products
//   k in [272,288): zero pad
#define K_TOT 288

typedef __attribute__((ext_vector_type(8))) short short8;   // bf16x8 MFMA frag
typedef __attribute__((ext_vector_type(4))) float floatx4;  // fp32x4 acc

__device__ __forceinline__ ushort f2bf(float f) {  // RNE float->bf16
  unsigned u = __float_as_uint(f);
  return (ushort)((u + 0x7FFFu + ((u >> 16) & 1u)) >> 16);
}

// ---------------- prep: Ab/Bb bf16 matrices, nzc, event bit-pack, out=0 ------
// grid 2048 x 256 threads, barrier-free. Block b:
//   all threads: bit-pack events row b (2 x int4/thread, shuffle-OR -> u32)
//   wave 0:      Ab row b (4 orders + Gram 4x4 + pad)
//   wave 1:      Bb row b (-2*coef_o*zc + coef products + pad), nzc[b]
__global__ void prep_kernel(const int* __restrict__ events,
                            const float* __restrict__ col_times,
                            const float* __restrict__ z_rows,
                            const float* __restrict__ z_cols,
                            ushort* __restrict__ Ab,
                            ushort* __restrict__ Bb,
                            float* __restrict__ nzc,
                            unsigned* __restrict__ Wb,
                            float* __restrict__ out) {
  const int b = blockIdx.x;
  const int t = threadIdx.x;
  const int lane = t & 63;

  if (b == 0 && t == 0) out[0] = 0.0f;  // stream order: before pair_kernel

  // ---- events bit-pack: row b = 8KB contiguous, 2 coalesced int4 rounds ----
  const int4 e0 = *(const int4*)&events[(size_t)b * C_DIM + t * 4];
  const int4 e1 = *(const int4*)&events[(size_t)b * C_DIM + 1024 + t * 4];
  {
    unsigned w0 = ((unsigned)(e0.x & 1) | ((unsigned)(e0.y & 1) << 1) |
                   ((unsigned)(e0.z & 1) << 2) | ((unsigned)(e0.w & 1) << 3))
                  << ((t & 7) * 4);
    w0 |= __shfl_xor((int)w0, 1); w0 |= __shfl_xor((int)w0, 2);
    w0 |= __shfl_xor((int)w0, 4);
    if ((t & 7) == 0) Wb[b * 64 + (t >> 3)] = w0;
    unsigned w1 = ((unsigned)(e1.x & 1) | ((unsigned)(e1.y & 1) << 1) |
                   ((unsigned)(e1.z & 1) << 2) | ((unsigned)(e1.w & 1) << 3))
                  << ((t & 7) * 4);
    w1 |= __shfl_xor((int)w1, 1); w1 |= __shfl_xor((int)w1, 2);
    w1 |= __shfl_xor((int)w1, 4);
    if ((t & 7) == 0) Wb[b * 64 + 32 + (t >> 3)] = w1;
  }

  if (t < 64) {
    // ---- Ab row b ----
    float zv[4];
#pragma unroll
    for (int o = 0; o < 4; ++o) {
      zv[o] = z_rows[(size_t)(o * R_DIM + b) * D_DIM + lane];
      Ab[(size_t)b * K_TOT + o * 64 + lane] = f2bf(zv[o]);
    }
    float g00 = zv[0] * zv[0], g01 = zv[0] * zv[1], g02 = zv[0] * zv[2],
          g03 = zv[0] * zv[3], g11 = zv[1] * zv[1], g12 = zv[1] * zv[2],
          g13 = zv[1] * zv[3], g22 = zv[2] * zv[2], g23 = zv[2] * zv[3],
          g33 = zv[3] * zv[3];
#pragma unroll
    for (int off = 32; off > 0; off >>= 1) {
      g00 += __shfl_xor(g00, off); g01 += __shfl_xor(g01, off);
      g02 += __shfl_xor(g02, off); g03 += __shfl_xor(g03, off);
      g11 += __shfl_xor(g11, off); g12 += __shfl_xor(g12, off);
      g13 += __shfl_xor(g13, off); g22 += __shfl_xor(g22, off);
      g23 += __shfl_xor(g23, off); g33 += __shfl_xor(g33, off);
    }
    if (lane == 0) {
      ushort* e = Ab + (size_t)b * K_TOT + 256;  // symmetric 4x4
      e[0] = f2bf(g00);  e[1] = f2bf(g01);  e[2] = f2bf(g02);  e[3] = f2bf(g03);
      e[4] = f2bf(g01);  e[5] = f2bf(g11);  e[6] = f2bf(g12);  e[7] = f2bf(g13);
      e[8] = f2bf(g02);  e[9] = f2bf(g12);  e[10] = f2bf(g22); e[11] = f2bf(g23);
      e[12] = f2bf(g03); e[13] = f2bf(g13); e[14] = f2bf(g23); e[15] = f2bf(g33);
    }
    if (lane < 16) Ab[(size_t)b * K_TOT + 272 + lane] = 0;  // pad
  } else if (t < 128) {
    // ---- Bb row b + nzc ----
    const float tt = col_times[b];
    float cf[4];
    cf[0] = 1.0f; cf[1] = tt; cf[2] = tt * tt * 0.5f;
    cf[3] = cf[2] * tt * (1.0f / 3.0f);
    const float zc = z_cols[(size_t)b * D_DIM + lane];
#pragma unroll
    for (int o = 0; o < 4; ++o)
      Bb[(size_t)b * K_TOT + o * 64 + lane] = f2bf(-2.0f * cf[o] * zc);
    float q = zc * zc;
#pragma unroll
    for (int off = 32; off > 0; off >>= 1) q += __shfl_xor(q, off);
    if (lane == 0) {
      nzc[b] = q;
      ushort* e = Bb + (size_t)b * K_TOT + 256;
#pragma unroll
      for (int i = 0; i < 16; ++i) e[i] = f2bf(cf[i >> 2] * cf[i & 3]);
    }
    if (lane < 16) Bb[(size_t)b * K_TOT + 272 + lane] = 0;  // pad
  }
}

// ---------------- pair: register-direct MFMA GEMM, zero-barrier K loop -------
// 64x64 block tile, 4 waves in 2x2 (32x32/wave), grid 32x32 = 1024 blocks.
// No LDS staging: Ab+Bb (2.4MB) are L2-resident per XCD; each fragment is one
// global_load_dwordx4 (wave covers 16 rows x 64B = whole cache lines). 9
// k-tiles fully unrolled -> ~36 independent loads in flight per wave, no
// lockstep barrier drains. Events from the 512KB bit-pack.
__launch_bounds__(256, 3)
__global__ void pair_kernel(const float* __restrict__ gamma_rows,
                            const float* __restrict__ gamma_cols,
                            const ushort* __restrict__ Ab,
                            const ushort* __restrict__ Bb,
                            const float* __restrict__ nzc,
                            const unsigned* __restrict__ Wb,
                            float* __restrict__ out) {
  __shared__ float red[4];
  const int t = threadIdx.x;
  const int widx = t >> 6, lane = t & 63;
  const int m0 = blockIdx.y * 64, c0 = blockIdx.x * 64;
  const int wm = widx & 1, wn = widx >> 1;  // wave pos in 2x2
  const int lm = lane & 15, kg = lane >> 4;

  // lane base pointers for MFMA fragments:
  // A-operand layout: lane holds A[m = lane&15][k = (lane>>4)*8 + j]
  const ushort* a0p = Ab + (size_t)(m0 + wm * 32 + lm) * K_TOT + kg * 8;
  const ushort* a1p = a0p + 16 * K_TOT;
  const ushort* b0p = Bb + (size_t)(c0 + wn * 32 + lm) * K_TOT + kg * 8;
  const ushort* b1p = b0p + 16 * K_TOT;

  floatx4 acc[2][2];
#pragma unroll
  for (int i = 0; i < 2; ++i)
#pragma unroll
    for (int j = 0; j < 2; ++j) acc[i][j] = (floatx4){0.f, 0.f, 0.f, 0.f};

#pragma unroll
  for (int kt = 0; kt < 9; ++kt) {
    const short8 a0 = *(const short8*)(a0p + kt * 32);
    const short8 a1 = *(const short8*)(a1p + kt * 32);
    const short8 b0 = *(const short8*)(b0p + kt * 32);
    const short8 b1 = *(const short8*)(b1p + kt * 32);
    acc[0][0] = __builtin_amdgcn_mfma_f32_16x16x32_bf16(a0, b0, acc[0][0], 0, 0, 0);
    acc[0][1] = __builtin_amdgcn_mfma_f32_16x16x32_bf16(a0, b1, acc[0][1], 0, 0, 0);
    acc[1][0] = __builtin_amdgcn_mfma_f32_16x16x32_bf16(a1, b0, acc[1][0], 0, 0, 0);
    acc[1][1] = __builtin_amdgcn_mfma_f32_16x16x32_bf16(a1, b1, acc[1][1], 0, 0, 0);
  }

  // Epilogue. C/D layout (m89): col = lane&15, row = (lane>>4)*4 + reg.
  // loss = softplus(logit) - ev*logit  (branchless; ev from bit-pack)
  float lsum = 0.0f;
#pragma unroll
  for (int nt = 0; nt < 2; ++nt) {
    const int c = c0 + wn * 32 + nt * 16 + lm;
    const float gc = gamma_cols[c];
    const float nz = nzc[c];
    const int cword = c >> 5, cbit = c & 31;
#pragma unroll
    for (int mt = 0; mt < 2; ++mt) {
      const int rbase = m0 + wm * 32 + mt * 16 + kg * 4;
#pragma unroll
      for (int j = 0; j < 4; ++j) {
        const int r = rbase + j;
        const float evf = (float)((Wb[r * 64 + cword] >> cbit) & 1u);
        const float d2 = acc[mt][nt][j] + nz;
        const float dist = sqrtf(fmaxf(d2, 0.0f));
        const float logit = gamma_rows[r] + gc - dist;
        lsum += fmaxf(logit, 0.0f) + __logf(1.0f + __expf(-fabsf(logit))) -
                evf * logit;
      }
    }
  }
#pragma unroll
  for (int off = 32; off > 0; off >>= 1) lsum += __shfl_down(lsum, off);
  if (lane == 0) red[widx] = lsum;
  __syncthreads();
  if (t == 0) atomicAdd(out, red[0] + red[1] + red[2] + red[3]);
}

extern "C" void kernel_launch(void* const* d_in, const int* in_sizes, int n_in,
                              void* d_out, int out_size, void* d_ws, size_t ws_size,
                              hipStream_t stream) {
  const int* events = (const int*)d_in[0];
  const float* col_times = (const float*)d_in[1];
  const float* z_rows = (const float*)d_in[2];
  const float* z_cols = (const float*)d_in[3];
  const float* gamma_rows = (const float*)d_in[4];
  const float* gamma_cols = (const float*)d_in[5];
  float* out = (float*)d_out;

  ushort* Ab = (ushort*)d_ws;                            // 2048*288 bf16
  ushort* Bb = Ab + (size_t)R_DIM * K_TOT;               // 2048*288 bf16
  float* nzc = (float*)(Bb + (size_t)C_DIM * K_TOT);     // 2048 f32
  unsigned* Wb = (unsigned*)(nzc + C_DIM);               // 2048*64 u32 bit-pack

  prep_kernel<<<R_DIM, 256, 0, stream>>>(events, col_times, z_rows, z_cols, Ab,
                                         Bb, nzc, Wb, out);
  dim3 grid(C_DIM / 64, R_DIM / 64);
  pair_kernel<<<grid, 256, 0, stream>>>(gamma_rows, gamma_cols, Ab, Bb, nzc, Wb,
                                        out);
}